// Round 13
// baseline (124.272 us; speedup 1.0000x reference)
//
#include <hip/hip_runtime.h>

// GraphRetrieval fused kernel, MI355X (gfx950). Round 13: MFMA dual-GEMM
// + T14 async R prefetch (issue-early inline-asm loads, wait-late consume).
// B=16384, K=8, D=128, C=128. All fp32; labels int32.
//
// Round-12 measurement (first MFMA datapoint): 42us, VALUBusy 17.8%,
// MfmaUtil 2.6%, HBM 14%, occ 38% -> all pipes idle; time invariant across
// 4 structures => exposed R-stream latency (Little's law: R loads outstanding
// only ~10% of block lifetime). Fix: issue all 32 R loads per wave at kernel
// entry via asm volatile (compiler can't sink them - round-5 failure mode),
// drain with one vmcnt(0)+sched_barrier(0) after Phase B (rule #18).

#define SB      16
#define THREADS 256

typedef __attribute__((ext_vector_type(8))) short bfrag_t;  // 8 bf16 (4 VGPR)
typedef __attribute__((ext_vector_type(4))) float facc_t;   // 4 f32 acc
typedef __attribute__((ext_vector_type(2))) float f32x2;    // asm-load dest

__device__ __forceinline__ unsigned short bf16_hi_trunc(float f) {
    return (unsigned short)(__builtin_bit_cast(unsigned int, f) >> 16);
}
__device__ __forceinline__ float bf16_up(unsigned short h) {
    return __builtin_bit_cast(float, ((unsigned int)h) << 16);
}

// ---- prep: pack [Wa|Wp] (fp32 [128][128] each) into split-bf16 fragment
// layout.  chunk t in [0,4096): nt=t>>8, kk=(t>>6)&3, lane=t&63.
// lane holds col nt*16+(lane&15), k = kk*32+(lane>>4)*8 + 0..7 (16B).
__global__ __launch_bounds__(256)
void pack_w_kernel(const float* __restrict__ Wa, const float* __restrict__ Wp,
                   unsigned short* __restrict__ w_hi, unsigned short* __restrict__ w_lo) {
    const int t    = blockIdx.x * 256 + threadIdx.x;
    const int nt   = t >> 8;
    const int kk   = (t >> 6) & 3;
    const int lane = t & 63;
    const int n    = nt * 16 + (lane & 15);
    const int kb   = kk * 32 + (lane >> 4) * 8;
    const float* W = (n < 128) ? Wa : Wp;
    const int col  = n & 127;
    unsigned int h[4], l[4];
    #pragma unroll
    for (int i = 0; i < 4; ++i) {
        const float v0 = W[(kb + 2 * i) * 128 + col];
        const float v1 = W[(kb + 2 * i + 1) * 128 + col];
        const unsigned short h0 = bf16_hi_trunc(v0), h1 = bf16_hi_trunc(v1);
        const unsigned short l0 = bf16_hi_trunc(v0 - bf16_up(h0));
        const unsigned short l1 = bf16_hi_trunc(v1 - bf16_up(h1));
        h[i] = (unsigned int)h0 | ((unsigned int)h1 << 16);
        l[i] = (unsigned int)l0 | ((unsigned int)l1 << 16);
    }
    ((uint4*)w_hi)[t] = make_uint4(h[0], h[1], h[2], h[3]);
    ((uint4*)w_lo)[t] = make_uint4(l[0], l[1], l[2], l[3]);
}

__global__ __launch_bounds__(THREADS, 3)
void graph_retrieval_fused(const float* __restrict__ G,      // [B,128]
                           const float* __restrict__ R,      // [B,8,128]
                           const unsigned short* __restrict__ w_hi,
                           const unsigned short* __restrict__ w_lo,
                           const float* __restrict__ bp,     // [128]
                           const int*   __restrict__ labels, // [B,8]
                           float* __restrict__ out)          // [B,128]
{
    __shared__ float g_lds[SB * 132];       // padded pitch 132 (bank spread)
    __shared__ float t_lds[SB * 132];
    __shared__ float logit_lds[SB * 132];
    __shared__ float attn_lds[SB * 8];
    __shared__ float stat_m[SB], stat_iz[SB];
    __shared__ int   lab_lds[SB * 8];

    const int tid  = threadIdx.x;
    const int b0   = blockIdx.x * SB;
    const int wv   = tid >> 6;
    const int lane = tid & 63;
    const int s0   = wv * 4;               // wave owns samples s0..s0+3

    // ---------- T14 issue-early: all 32 R loads in flight from cycle ~0 ----
    // r_pref[q][mm] = R[b0+s0+q][mm][2*lane .. 2*lane+1]
    // asm volatile so the compiler cannot sink them to the use site
    // (round-5 failure). Consumed after Phase B behind vmcnt(0).
    f32x2 r_pref[4][8];
    {
        const float* Rbase = R + (size_t)(b0 + s0) * 1024 + lane * 2;
        #pragma unroll
        for (int q = 0; q < 4; ++q) {
            const float* bq = Rbase + q * 1024;
            #pragma unroll
            for (int mm = 0; mm < 8; ++mm) {
                asm volatile("global_load_dwordx2 %0, %1, off offset:%2"
                             : "=v"(r_pref[q][mm])
                             : "v"(bq), "i"(mm * 512));
            }
        }
    }

    // ---------- Phase A: stage g (padded) + labels ----------
    {
        const float4* Gv = (const float4*)(G + (size_t)b0 * 128);
        #pragma unroll
        for (int rpt = 0; rpt < 2; ++rpt) {
            const int idx = rpt * 256 + tid;          // 0..511 over [16][32] f4
            const int row = idx >> 5, j = idx & 31;
            ((float4*)g_lds)[row * 33 + j] = Gv[idx]; // pitch 33 f4 = 132 f
        }
        if (tid < SB * 8) lab_lds[tid] = labels[b0 * 8 + tid];
    }
    __syncthreads();

    // ---------- Phase B: dual GEMM via split-bf16 MFMA ----------
    {
        // A fragments: row = lane&15 (sample), k = (lane>>4)*8 + j + 32*kk
        const int arow = lane & 15;
        const int kch  = lane >> 4;
        bfrag_t a_hi[4], a_lo[4];
        #pragma unroll
        for (int kk = 0; kk < 4; ++kk) {
            const float* src = &g_lds[arow * 132 + kk * 32 + kch * 8];
            const float4 f0 = *(const float4*)src;
            const float4 f1 = *(const float4*)(src + 4);
            const float f[8] = {f0.x, f0.y, f0.z, f0.w, f1.x, f1.y, f1.z, f1.w};
            #pragma unroll
            for (int i = 0; i < 8; ++i) {
                const unsigned short hb = bf16_hi_trunc(f[i]);
                a_hi[kk][i] = (short)hb;
                a_lo[kk][i] = (short)bf16_hi_trunc(f[i] - bf16_up(hb));
            }
        }

        facc_t acc[4] = {{0.f,0.f,0.f,0.f},{0.f,0.f,0.f,0.f},
                         {0.f,0.f,0.f,0.f},{0.f,0.f,0.f,0.f}};
        #pragma unroll
        for (int p = 0; p < 4; ++p) {
            const int nt = wv * 4 + p;
            #pragma unroll
            for (int kk = 0; kk < 4; ++kk) {
                const int idx = (nt * 4 + kk) * 64 + lane;
                const bfrag_t bh = ((const bfrag_t*)w_hi)[idx];
                const bfrag_t bl = ((const bfrag_t*)w_lo)[idx];
                acc[p] = __builtin_amdgcn_mfma_f32_16x16x32_bf16(a_hi[kk], bh, acc[p], 0, 0, 0);
                acc[p] = __builtin_amdgcn_mfma_f32_16x16x32_bf16(a_lo[kk], bh, acc[p], 0, 0, 0);
                acc[p] = __builtin_amdgcn_mfma_f32_16x16x32_bf16(a_hi[kk], bl, acc[p], 0, 0, 0);
            }
        }

        // write back: C/D layout col=lane&15, row=(lane>>4)*4+j  [m89]
        const int crow = (lane >> 4) * 4;
        #pragma unroll
        for (int p = 0; p < 4; ++p) {
            const int coll = p * 16 + (lane & 15);     // within wave's 64 cols
            if (wv < 2) {                              // t = g@Wa
                const int c_t = wv * 64 + coll;
                #pragma unroll
                for (int j = 0; j < 4; ++j)
                    t_lds[(crow + j) * 132 + c_t] = acc[p][j];
            } else {                                   // logits = g@Wp + b
                const int c_l = (wv - 2) * 64 + coll;
                const float bias = bp[c_l];
                #pragma unroll
                for (int j = 0; j < 4; ++j)
                    logit_lds[(crow + j) * 132 + c_l] = acc[p][j] + bias;
            }
        }
    }
    __syncthreads();

    // ---------- Phase C/D: per-wave {logit stats + scores + attn}, 4 samples ----------
    {
        // logit softmax stats (batched over 4 samples) — no r_pref use yet,
        // runs while any straggler R loads are still in flight
        float mx[4], zs[4];
        float2 ev[4];
        #pragma unroll
        for (int q = 0; q < 4; ++q) {
            ev[q] = *(const float2*)&logit_lds[(s0 + q) * 132 + 2 * lane];
            mx[q] = fmaxf(ev[q].x, ev[q].y);
        }
        #pragma unroll
        for (int off = 32; off > 0; off >>= 1)
            #pragma unroll
            for (int q = 0; q < 4; ++q)
                mx[q] = fmaxf(mx[q], __shfl_xor(mx[q], off, 64));
        #pragma unroll
        for (int q = 0; q < 4; ++q)
            zs[q] = __expf(ev[q].x - mx[q]) + __expf(ev[q].y - mx[q]);
        #pragma unroll
        for (int off = 32; off > 0; off >>= 1)
            #pragma unroll
            for (int q = 0; q < 4; ++q)
                zs[q] += __shfl_xor(zs[q], off, 64);
        if (lane == 0) {
            #pragma unroll
            for (int q = 0; q < 4; ++q) {
                stat_m[s0 + q]  = mx[q];
                stat_iz[s0 + q] = 1.f / zs[q];
            }
        }

        // ---- T14 wait-late: drain R prefetch, then consume from registers
        asm volatile("s_waitcnt vmcnt(0)" ::: "memory");
        __builtin_amdgcn_sched_barrier(0);              // rule #18

        float sc[4][9];
        #pragma unroll
        for (int q = 0; q < 4; ++q) {
            const int s = s0 + q;
            const float2 t2 = *(const float2*)&t_lds[s * 132 + 2 * lane];
            const float2 g2 = *(const float2*)&g_lds[s * 132 + 2 * lane];
            sc[q][0] = t2.x * g2.x + t2.y * g2.y;
            #pragma unroll
            for (int m = 1; m < 9; ++m)
                sc[q][m] = t2.x * r_pref[q][m - 1][0] + t2.y * r_pref[q][m - 1][1];
        }
        #pragma unroll
        for (int off = 32; off > 0; off >>= 1)
            #pragma unroll
            for (int q = 0; q < 4; ++q)
                #pragma unroll
                for (int m = 0; m < 9; ++m)
                    sc[q][m] += __shfl_xor(sc[q][m], off, 64);

        #pragma unroll
        for (int q = 0; q < 4; ++q) {
            float m9 = sc[q][0];
            #pragma unroll
            for (int m = 1; m < 9; ++m) m9 = fmaxf(m9, sc[q][m]);
            float e[9], sum = 0.f;
            #pragma unroll
            for (int m = 0; m < 9; ++m) { e[m] = __expf(sc[q][m] - m9); sum += e[m]; }
            const float inv = 1.f / sum;
            if (lane == 0) {
                #pragma unroll
                for (int m = 0; m < 8; ++m)          // attn[8] only normalizes
                    attn_lds[(s0 + q) * 8 + m] = e[m] * inv;
            }
        }
    }
    __syncthreads();

    // ---------- Phase E: epilogue ----------
    {
        const int c  = tid & 127;
        const int hh = tid >> 7;
        #pragma unroll
        for (int i = 0; i < 8; ++i) {
            const int s = hh * 8 + i;
            const float lg = logit_lds[s * 132 + c];
            const float gl = __expf(lg - stat_m[s]) * stat_iz[s];
            const int4   la = *(const int4*)&lab_lds[s * 8];
            const int4   lb = *(const int4*)&lab_lds[s * 8 + 4];
            const float4 a0 = *(const float4*)&attn_lds[s * 8];
            const float4 a1 = *(const float4*)&attn_lds[s * 8 + 4];
            float val = a0.x * gl;
            val += (la.x == c) ? a0.x : 0.f;
            val += (la.y == c) ? a0.y : 0.f;
            val += (la.z == c) ? a0.z : 0.f;
            val += (la.w == c) ? a0.w : 0.f;
            val += (lb.x == c) ? a1.x : 0.f;
            val += (lb.y == c) ? a1.y : 0.f;
            val += (lb.z == c) ? a1.z : 0.f;
            val += (lb.w == c) ? a1.w : 0.f;
            out[(size_t)(b0 + s) * 128 + c] = val;
        }
    }
}

extern "C" void kernel_launch(void* const* d_in, const int* in_sizes, int n_in,
                              void* d_out, int out_size, void* d_ws, size_t ws_size,
                              hipStream_t stream) {
    const float* G      = (const float*)d_in[0];
    const float* R      = (const float*)d_in[1];
    const float* Wa     = (const float*)d_in[2];
    const float* Wp     = (const float*)d_in[3];
    const float* bpred  = (const float*)d_in[4];
    const int*   labels = (const int*)d_in[5];
    float*       o      = (float*)d_out;

    unsigned short* w_hi = (unsigned short*)d_ws;          // 64 KB
    unsigned short* w_lo = w_hi + 4096 * 8;                // next 64 KB

    hipLaunchKernelGGL(pack_w_kernel, dim3(16), dim3(256), 0, stream,
                       Wa, Wp, w_hi, w_lo);

    const int B = in_sizes[0] / 128;   // 16384
    hipLaunchKernelGGL(graph_retrieval_fused, dim3(B / SB), dim3(THREADS), 0, stream,
                       G, R, w_hi, w_lo, bpred, labels, o);
}

// Round 14
// 116.597 us; speedup vs baseline: 1.0658x; 1.0658x over previous
//
#include <hip/hip_runtime.h>

// GraphRetrieval fused kernel, MI355X (gfx950). Round 14.
// B=16384, K=8, D=128, C=128. All fp32; labels int32.
//
// r12/r13 post-mortem: 42us invariant, all pipes <20% busy, occupancy 23%.
// Diagnosis: 216-dependent-shuffle score butterfly + only 16 waves/CU of
// total work. Round 14: (1) grouped score reduce - 8 lanes per retrieval m,
// 3-level shfl_xor instead of 6-level 64-lane butterfly (216 -> ~30 DS ops);
// (2) 512-thread blocks (8 waves, 2 samples/wave) -> 32 waves/CU of work.
// Dual GEMM stays split-bf16 MFMA (r12: correct, absmax 3.9e-3).

#define SB      16
#define THREADS 512

typedef __attribute__((ext_vector_type(8))) short bfrag_t;  // 8 bf16 (4 VGPR)
typedef __attribute__((ext_vector_type(4))) float facc_t;   // 4 f32 acc

__device__ __forceinline__ unsigned short bf16_hi_trunc(float f) {
    return (unsigned short)(__builtin_bit_cast(unsigned int, f) >> 16);
}
__device__ __forceinline__ float bf16_up(unsigned short h) {
    return __builtin_bit_cast(float, ((unsigned int)h) << 16);
}
__device__ __forceinline__ float dot4(float4 a, float4 b) {
    return a.x * b.x + a.y * b.y + a.z * b.z + a.w * b.w;
}

// ---- prep: pack [Wa|Wp] (fp32 [128][128] each) into split-bf16 fragment
// layout.  chunk t in [0,4096): nt=t>>8, kk=(t>>6)&3, lane=t&63.
// lane holds col nt*16+(lane&15), k = kk*32+(lane>>4)*8 + 0..7 (16B).
__global__ __launch_bounds__(256)
void pack_w_kernel(const float* __restrict__ Wa, const float* __restrict__ Wp,
                   unsigned short* __restrict__ w_hi, unsigned short* __restrict__ w_lo) {
    const int t    = blockIdx.x * 256 + threadIdx.x;
    const int nt   = t >> 8;
    const int kk   = (t >> 6) & 3;
    const int lane = t & 63;
    const int n    = nt * 16 + (lane & 15);
    const int kb   = kk * 32 + (lane >> 4) * 8;
    const float* W = (n < 128) ? Wa : Wp;
    const int col  = n & 127;
    unsigned int h[4], l[4];
    #pragma unroll
    for (int i = 0; i < 4; ++i) {
        const float v0 = W[(kb + 2 * i) * 128 + col];
        const float v1 = W[(kb + 2 * i + 1) * 128 + col];
        const unsigned short h0 = bf16_hi_trunc(v0), h1 = bf16_hi_trunc(v1);
        const unsigned short l0 = bf16_hi_trunc(v0 - bf16_up(h0));
        const unsigned short l1 = bf16_hi_trunc(v1 - bf16_up(h1));
        h[i] = (unsigned int)h0 | ((unsigned int)h1 << 16);
        l[i] = (unsigned int)l0 | ((unsigned int)l1 << 16);
    }
    ((uint4*)w_hi)[t] = make_uint4(h[0], h[1], h[2], h[3]);
    ((uint4*)w_lo)[t] = make_uint4(l[0], l[1], l[2], l[3]);
}

__global__ __launch_bounds__(THREADS, 4)
void graph_retrieval_fused(const float* __restrict__ G,      // [B,128]
                           const float* __restrict__ R,      // [B,8,128]
                           const unsigned short* __restrict__ w_hi,
                           const unsigned short* __restrict__ w_lo,
                           const float* __restrict__ bp,     // [128]
                           const int*   __restrict__ labels, // [B,8]
                           float* __restrict__ out)          // [B,128]
{
    __shared__ float g_lds[SB * 132];       // padded pitch 132
    __shared__ float t_lds[SB * 132];
    __shared__ float logit_lds[SB * 132];
    __shared__ float attn_lds[SB * 8];
    __shared__ float stat_m[SB], stat_iz[SB];
    __shared__ int   lab_lds[SB * 8];

    const int tid  = threadIdx.x;
    const int b0   = blockIdx.x * SB;
    const int wv   = tid >> 6;              // 0..7
    const int lane = tid & 63;
    const int s0   = wv * 2;                // wave owns samples s0, s0+1

    // ---------- Phase A: stage g (padded) + labels ----------
    {
        const float4* Gv = (const float4*)(G + (size_t)b0 * 128);
        const int row = tid >> 5, jj = tid & 31;      // 512 f4 over [16][32]
        ((float4*)g_lds)[row * 33 + jj] = Gv[tid];    // pitch 33 f4 = 132 f
        if (tid < SB * 8) lab_lds[tid] = labels[b0 * 8 + tid];
    }
    __syncthreads();

    // ---------- Phase B: dual GEMM via split-bf16 MFMA ----------
    {
        // A fragments: row = lane&15 (sample), k = (lane>>4)*8 + i + 32*kk
        const int arow = lane & 15;
        const int kch  = lane >> 4;
        bfrag_t a_hi[4], a_lo[4];
        #pragma unroll
        for (int kk = 0; kk < 4; ++kk) {
            const float* src = &g_lds[arow * 132 + kk * 32 + kch * 8];
            const float4 f0 = *(const float4*)src;
            const float4 f1 = *(const float4*)(src + 4);
            const float f[8] = {f0.x, f0.y, f0.z, f0.w, f1.x, f1.y, f1.z, f1.w};
            #pragma unroll
            for (int i = 0; i < 8; ++i) {
                const unsigned short hb = bf16_hi_trunc(f[i]);
                a_hi[kk][i] = (short)hb;
                a_lo[kk][i] = (short)bf16_hi_trunc(f[i] - bf16_up(hb));
            }
        }

        facc_t acc[2] = {{0.f,0.f,0.f,0.f},{0.f,0.f,0.f,0.f}};
        #pragma unroll
        for (int p = 0; p < 2; ++p) {
            const int nt = wv * 2 + p;                 // 0..15 over [t|logit]
            #pragma unroll
            for (int kk = 0; kk < 4; ++kk) {
                const int idx = (nt * 4 + kk) * 64 + lane;
                const bfrag_t bh = ((const bfrag_t*)w_hi)[idx];
                const bfrag_t bl = ((const bfrag_t*)w_lo)[idx];
                acc[p] = __builtin_amdgcn_mfma_f32_16x16x32_bf16(a_hi[kk], bh, acc[p], 0, 0, 0);
                acc[p] = __builtin_amdgcn_mfma_f32_16x16x32_bf16(a_lo[kk], bh, acc[p], 0, 0, 0);
                acc[p] = __builtin_amdgcn_mfma_f32_16x16x32_bf16(a_hi[kk], bl, acc[p], 0, 0, 0);
            }
        }

        // write back: C/D layout col=lane&15, row=(lane>>4)*4+j  [m89]
        const int crow = (lane >> 4) * 4;
        const int coll = lane & 15;
        #pragma unroll
        for (int p = 0; p < 2; ++p) {
            const int nt = wv * 2 + p;
            if (nt < 8) {                              // t = g@Wa, cols 0..127
                const int c_t = nt * 16 + coll;
                #pragma unroll
                for (int j = 0; j < 4; ++j)
                    t_lds[(crow + j) * 132 + c_t] = acc[p][j];
            } else {                                   // logits = g@Wp + b
                const int c_l = (nt - 8) * 16 + coll;
                const float bias = bp[c_l];
                #pragma unroll
                for (int j = 0; j < 4; ++j)
                    logit_lds[(crow + j) * 132 + c_l] = acc[p][j] + bias;
            }
        }
    }
    __syncthreads();

    // ---------- Phase C: logit softmax stats (2 samples/wave) ----------
    {
        float mx[2], zs[2];
        float2 ev[2];
        #pragma unroll
        for (int q = 0; q < 2; ++q) {
            ev[q] = *(const float2*)&logit_lds[(s0 + q) * 132 + 2 * lane];
            mx[q] = fmaxf(ev[q].x, ev[q].y);
        }
        #pragma unroll
        for (int off = 32; off > 0; off >>= 1)
            #pragma unroll
            for (int q = 0; q < 2; ++q)
                mx[q] = fmaxf(mx[q], __shfl_xor(mx[q], off, 64));
        #pragma unroll
        for (int q = 0; q < 2; ++q)
            zs[q] = __expf(ev[q].x - mx[q]) + __expf(ev[q].y - mx[q]);
        #pragma unroll
        for (int off = 32; off > 0; off >>= 1)
            #pragma unroll
            for (int q = 0; q < 2; ++q)
                zs[q] += __shfl_xor(zs[q], off, 64);
        if (lane == 0) {
            #pragma unroll
            for (int q = 0; q < 2; ++q) {
                stat_m[s0 + q]  = mx[q];
                stat_iz[s0 + q] = 1.f / zs[q];
            }
        }
    }

    // ---------- Phase D: grouped scores + attention softmax ----------
    // group g = lane>>3 owns retrieval m=g+1; lane j = lane&7 covers dims
    // [j*16, j*16+16). m=0 (t.g) slices are group-independent, so the same
    // 3-level intra-group reduce yields the full m=0 dot on every lane.
    {
        const int gg = lane >> 3, jj2 = lane & 7;
        float sc0[2], scm[2];
        #pragma unroll
        for (int q = 0; q < 2; ++q) {
            const int s = s0 + q;
            const float* tb = &t_lds[s * 132 + jj2 * 16];
            const float* gb = &g_lds[s * 132 + jj2 * 16];
            const float* rb = R + (size_t)(b0 + s) * 1024 + gg * 128 + jj2 * 16;
            float p0 = 0.f, pm = 0.f;
            #pragma unroll
            for (int e = 0; e < 4; ++e) {
                const float4 tv = *(const float4*)(tb + e * 4);
                const float4 gv = *(const float4*)(gb + e * 4);
                const float4 rv = *(const float4*)(rb + e * 4);
                p0 += dot4(tv, gv);
                pm += dot4(tv, rv);
            }
            sc0[q] = p0; scm[q] = pm;
        }
        #pragma unroll
        for (int off = 1; off < 8; off <<= 1) {
            #pragma unroll
            for (int q = 0; q < 2; ++q) {
                sc0[q] += __shfl_xor(sc0[q], off, 64);
                scm[q] += __shfl_xor(scm[q], off, 64);
            }
        }
        // broadcast: sc9[m] for m=1..8 lives in group m-1 (all its lanes)
        #pragma unroll
        for (int q = 0; q < 2; ++q) {
            const int s = s0 + q;
            float sc9[9];
            sc9[0] = sc0[q];
            #pragma unroll
            for (int m = 1; m < 9; ++m)
                sc9[m] = __shfl(scm[q], (m - 1) * 8, 64);
            float m9 = sc9[0];
            #pragma unroll
            for (int m = 1; m < 9; ++m) m9 = fmaxf(m9, sc9[m]);
            float e[9], sum = 0.f;
            #pragma unroll
            for (int m = 0; m < 9; ++m) { e[m] = __expf(sc9[m] - m9); sum += e[m]; }
            const float inv = 1.f / sum;
            if (lane == 0) {
                #pragma unroll
                for (int m = 0; m < 8; ++m)          // attn[8] only normalizes
                    attn_lds[s * 8 + m] = e[m] * inv;
            }
        }
    }
    __syncthreads();

    // ---------- Phase E: epilogue ----------
    {
        const int c  = tid & 127;
        const int hh = tid >> 7;                      // 0..3
        #pragma unroll
        for (int i = 0; i < 4; ++i) {
            const int s = hh * 4 + i;
            const float lg = logit_lds[s * 132 + c];
            const float gl = __expf(lg - stat_m[s]) * stat_iz[s];
            const int4   la = *(const int4*)&lab_lds[s * 8];
            const int4   lb = *(const int4*)&lab_lds[s * 8 + 4];
            const float4 a0 = *(const float4*)&attn_lds[s * 8];
            const float4 a1 = *(const float4*)&attn_lds[s * 8 + 4];
            float val = a0.x * gl;
            val += (la.x == c) ? a0.x : 0.f;
            val += (la.y == c) ? a0.y : 0.f;
            val += (la.z == c) ? a0.z : 0.f;
            val += (la.w == c) ? a0.w : 0.f;
            val += (lb.x == c) ? a1.x : 0.f;
            val += (lb.y == c) ? a1.y : 0.f;
            val += (lb.z == c) ? a1.z : 0.f;
            val += (lb.w == c) ? a1.w : 0.f;
            out[(size_t)(b0 + s) * 128 + c] = val;
        }
    }
}

extern "C" void kernel_launch(void* const* d_in, const int* in_sizes, int n_in,
                              void* d_out, int out_size, void* d_ws, size_t ws_size,
                              hipStream_t stream) {
    const float* G      = (const float*)d_in[0];
    const float* R      = (const float*)d_in[1];
    const float* Wa     = (const float*)d_in[2];
    const float* Wp     = (const float*)d_in[3];
    const float* bpred  = (const float*)d_in[4];
    const int*   labels = (const int*)d_in[5];
    float*       o      = (float*)d_out;

    unsigned short* w_hi = (unsigned short*)d_ws;          // 64 KB
    unsigned short* w_lo = w_hi + 4096 * 8;                // next 64 KB

    hipLaunchKernelGGL(pack_w_kernel, dim3(16), dim3(256), 0, stream,
                       Wa, Wp, w_hi, w_lo);

    const int B = in_sizes[0] / 128;   // 16384
    hipLaunchKernelGGL(graph_retrieval_fused, dim3(B / SB), dim3(THREADS), 0, stream,
                       G, R, w_hi, w_lo, bpred, labels, o);
}